// Round 2
// baseline (66.819 us; speedup 1.0000x reference)
//
#include <hip/hip_runtime.h>
#include <math.h>

// Problem constants (from reference)
#define BATCH 128
#define LL    4096
#define DIM   64
#define EPS   1e-3f

// d_ws layout (floats):
//  [0    .. 1536) : CW[br][d][8] = {W0..W4 (BN-folded conv taps), Bf (folded bias), f_w[d], pad}
//  [1536 .. 1792) : MOD[d][4]    = {A_d, C_d, MD_d0, MD_d1}   (folded mp+BN, md*BN-scale)
//  [1792 .. 1795) : FB[3]        = f1_b, f2_b, fI_b
//  [1795 .. 1797) : D0, D1       = folded md bias+BN

__device__ __forceinline__ float elu_f(float z) {
    return z > 0.0f ? z : (__expf(z) - 1.0f);
}

__global__ void enc_fold(
    const float* __restrict__ cw0, const float* __restrict__ cb0, const float* __restrict__ cg0,
    const float* __restrict__ cbe0, const float* __restrict__ cm0, const float* __restrict__ cv0,
    const float* __restrict__ cw1, const float* __restrict__ cb1, const float* __restrict__ cg1,
    const float* __restrict__ cbe1, const float* __restrict__ cm1, const float* __restrict__ cv1,
    const float* __restrict__ cw2, const float* __restrict__ cb2, const float* __restrict__ cg2,
    const float* __restrict__ cbe2, const float* __restrict__ cm2, const float* __restrict__ cv2,
    const float* __restrict__ f0w, const float* __restrict__ f0b,
    const float* __restrict__ f1w, const float* __restrict__ f1b,
    const float* __restrict__ f2w, const float* __restrict__ f2b,
    const float* __restrict__ mpw, const float* __restrict__ mpb, const float* __restrict__ mpg,
    const float* __restrict__ mpbe, const float* __restrict__ mpm, const float* __restrict__ mpv,
    const float* __restrict__ mdw, const float* __restrict__ mdb, const float* __restrict__ mdg,
    const float* __restrict__ mdbe, const float* __restrict__ mdm, const float* __restrict__ mdv,
    float* __restrict__ W)
{
    const int t = threadIdx.x;
    if (t < 192) {
        const int br = t >> 6;
        const int d  = t & 63;
        const float* cw  = (br == 0) ? cw0  : (br == 1) ? cw1  : cw2;
        const float* cb  = (br == 0) ? cb0  : (br == 1) ? cb1  : cb2;
        const float* cg  = (br == 0) ? cg0  : (br == 1) ? cg1  : cg2;
        const float* cbe = (br == 0) ? cbe0 : (br == 1) ? cbe1 : cbe2;
        const float* cm  = (br == 0) ? cm0  : (br == 1) ? cm1  : cm2;
        const float* cv  = (br == 0) ? cv0  : (br == 1) ? cv1  : cv2;
        const float* fw  = (br == 0) ? f0w  : (br == 1) ? f1w  : f2w;
        const float s = cg[d] / sqrtf(cv[d] + EPS);
        float* o = W + t * 8;
        #pragma unroll
        for (int k = 0; k < 5; ++k) o[k] = cw[k * 64 + d] * s;
        o[5] = (cb[d] - cm[d]) * s + cbe[d];
        o[6] = fw[d];          // (64,1) dense weight
        o[7] = 0.0f;
    } else {
        const int d = t - 192;
        const float smp = mpg[d] / sqrtf(mpv[d] + EPS);
        const float A = mpw[d] * smp;
        const float C = (mpb[d] - mpm[d]) * smp + mpbe[d];
        const float s0 = mdg[0] / sqrtf(mdv[0] + EPS);
        const float s1 = mdg[1] / sqrtf(mdv[1] + EPS);
        float* o = W + 1536 + d * 4;
        o[0] = A;
        o[1] = C;
        o[2] = mdw[d * 2 + 0] * s0;
        o[3] = mdw[d * 2 + 1] * s1;
        if (d == 0) {
            W[1792] = f0b[0];
            W[1793] = f1b[0];
            W[1794] = f2b[0];
            W[1795] = (mdb[0] - mdm[0]) * s0 + mdbe[0];
            W[1796] = (mdb[1] - mdm[1]) * s1 + mdbe[1];
        }
    }
}

// 2048 blocks x 256 threads; each block: one batch row tile of 256 positions,
// each thread: 1 position, all 3 branches + modulation fused.
// 8 blocks/CU (16KB LDS each -> 128KB/CU), 32 waves/CU = 100% occupancy cap.
__global__ __launch_bounds__(256) void enc_main(
    const float* __restrict__ x, const int* __restrict__ perm,
    const float* __restrict__ W, float* __restrict__ out)
{
    __shared__ float xs[LL];
    const int t    = threadIdx.x;
    const int b    = blockIdx.x >> 4;
    const int tile = blockIdx.x & 15;

    // stage full transformed row into LDS (needed for interleaver gathers)
    const float4* xr4 = (const float4*)(x + (size_t)b * LL);
    float4* xs4 = (float4*)xs;
    #pragma unroll
    for (int i = 0; i < 4; ++i) {
        float4 v = xr4[t + 256 * i];
        v.x = 2.0f * v.x - 1.0f;
        v.y = 2.0f * v.y - 1.0f;
        v.z = 2.0f * v.z - 1.0f;
        v.w = 2.0f * v.w - 1.0f;
        xs4[t + 256 * i] = v;
    }
    __syncthreads();

    const int l0 = tile * 256 + t;

    // 5-wide circular window for position l0
    float xw[5], xi[5];
    const int* prow = perm + (size_t)b * LL;
    #pragma unroll
    for (int k = 0; k < 5; ++k) {
        const int idx = (l0 + k - 2) & (LL - 1);
        xw[k] = xs[idx];
        xi[k] = xs[prow[idx]];
    }

    // ---- stage 1: three conv branches -> e0, e1, e2 ----
    float e0 = W[1792], e1 = W[1793], e2 = W[1794];
    #pragma unroll 8
    for (int d = 0; d < 64; ++d) {
        const float* w0 = W + d * 8;
        const float* w1 = W + 512 + d * 8;
        const float* w2 = W + 1024 + d * 8;
        float h;
        h = fmaf(w0[0], xw[0], fmaf(w0[1], xw[1], fmaf(w0[2], xw[2], fmaf(w0[3], xw[3], fmaf(w0[4], xw[4], w0[5])))));
        e0 = fmaf(w0[6], elu_f(h), e0);
        h = fmaf(w1[0], xw[0], fmaf(w1[1], xw[1], fmaf(w1[2], xw[2], fmaf(w1[3], xw[3], fmaf(w1[4], xw[4], w1[5])))));
        e1 = fmaf(w1[6], elu_f(h), e1);
        h = fmaf(w2[0], xi[0], fmaf(w2[1], xi[1], fmaf(w2[2], xi[2], fmaf(w2[3], xi[3], fmaf(w2[4], xi[4], w2[5])))));
        e2 = fmaf(w2[6], elu_f(h), e2);
    }

    // ---- stage 2: modulation (pointwise in e) ----
    // output order: (br0 c0,c1)(br1 c0,c1)(br2 c0,c1)
    float2 c0, c1, c2;
    {
        const float D0 = W[1795], D1 = W[1796];
        c0 = make_float2(D0, D1);
        c1 = make_float2(D0, D1);
        c2 = make_float2(D0, D1);
    }
    #pragma unroll 8
    for (int d = 0; d < 64; ++d) {
        const float* md = W + 1536 + d * 4;
        const float A = md[0], C = md[1], m0 = md[2], m1 = md[3];
        float mo;
        mo = elu_f(fmaf(A, e0, C)); c0.x = fmaf(m0, mo, c0.x); c0.y = fmaf(m1, mo, c0.y);
        mo = elu_f(fmaf(A, e1, C)); c1.x = fmaf(m0, mo, c1.x); c1.y = fmaf(m1, mo, c1.y);
        mo = elu_f(fmaf(A, e2, C)); c2.x = fmaf(m0, mo, c2.x); c2.y = fmaf(m1, mo, c2.y);
    }

    // 6 contiguous floats per thread -> 3x dwordx2, coalesced
    float2* o2 = (float2*)(out + (size_t)b * 24576 + (size_t)l0 * 6);
    o2[0] = c0;
    o2[1] = c1;
    o2[2] = c2;
}

extern "C" void kernel_launch(void* const* d_in, const int* in_sizes, int n_in,
                              void* d_out, int out_size, void* d_ws, size_t ws_size,
                              hipStream_t stream) {
    const float* x    = (const float*)d_in[0];
    const int*   perm = (const int*)d_in[1];
    float* W = (float*)d_ws;

    enc_fold<<<1, 256, 0, stream>>>(
        (const float*)d_in[2],  (const float*)d_in[3],  (const float*)d_in[4],
        (const float*)d_in[5],  (const float*)d_in[6],  (const float*)d_in[7],
        (const float*)d_in[8],  (const float*)d_in[9],  (const float*)d_in[10],
        (const float*)d_in[11], (const float*)d_in[12], (const float*)d_in[13],
        (const float*)d_in[14], (const float*)d_in[15], (const float*)d_in[16],
        (const float*)d_in[17], (const float*)d_in[18], (const float*)d_in[19],
        (const float*)d_in[20], (const float*)d_in[21],
        (const float*)d_in[22], (const float*)d_in[23],
        (const float*)d_in[24], (const float*)d_in[25],
        (const float*)d_in[26], (const float*)d_in[27], (const float*)d_in[28],
        (const float*)d_in[29], (const float*)d_in[30], (const float*)d_in[31],
        (const float*)d_in[32], (const float*)d_in[33], (const float*)d_in[34],
        (const float*)d_in[35], (const float*)d_in[36], (const float*)d_in[37],
        W);

    enc_main<<<BATCH * (LL / 256), 256, 0, stream>>>(x, perm, W, (float*)d_out);
}

// Round 3
// 56.116 us; speedup vs baseline: 1.1907x; 1.1907x over previous
//
#include <hip/hip_runtime.h>
#include <math.h>

// Problem constants (from reference)
#define BATCH 128
#define LL    4096
#define DIM   64
#define EPS   1e-3f
#define LUTN  2048

// d_ws layout (floats):
//  [0    .. 1536) : CW[br][d][8] = {W0..W4 (BN-folded conv taps, pre-scaled by log2e),
//                                   B' (folded bias, scaled by log2e), fw, fw*ln2}
//  [1536 .. 1792) : MOD[d][4]    = {A_d, C_d, MD_d0, MD_d1}
//  [1792 .. 1795) : FB'[3]       = f_b - sum_d fw_d   (per branch)
//  [1795 .. 1797) : D0, D1       = folded md bias+BN
//  [1797]         : invh  (LUT index scale)
//  [1798]         : nlo   (= -lo*invh, for single-fma index)
//  [1799]         : lo
//  [1800 .. 1800+4*LUTN) : LUT float4 {F0(e_i), F1(e_i), dF0_i, dF1_i}

#define LOG2E 1.44269504088896340736f
#define LN2   0.69314718055994530942f

__device__ __forceinline__ float elu_plain(float z) {
    return z > 0.0f ? z : (__expf(z) - 1.0f);
}

__global__ void enc_fold(
    const float* __restrict__ cw0, const float* __restrict__ cb0, const float* __restrict__ cg0,
    const float* __restrict__ cbe0, const float* __restrict__ cm0, const float* __restrict__ cv0,
    const float* __restrict__ cw1, const float* __restrict__ cb1, const float* __restrict__ cg1,
    const float* __restrict__ cbe1, const float* __restrict__ cm1, const float* __restrict__ cv1,
    const float* __restrict__ cw2, const float* __restrict__ cb2, const float* __restrict__ cg2,
    const float* __restrict__ cbe2, const float* __restrict__ cm2, const float* __restrict__ cv2,
    const float* __restrict__ f0w, const float* __restrict__ f0b,
    const float* __restrict__ f1w, const float* __restrict__ f1b,
    const float* __restrict__ f2w, const float* __restrict__ f2b,
    const float* __restrict__ mpw, const float* __restrict__ mpb, const float* __restrict__ mpg,
    const float* __restrict__ mpbe, const float* __restrict__ mpm, const float* __restrict__ mpv,
    const float* __restrict__ mdw, const float* __restrict__ mdb, const float* __restrict__ mdg,
    const float* __restrict__ mdbe, const float* __restrict__ mdm, const float* __restrict__ mdv,
    float* __restrict__ W)
{
    const int t = threadIdx.x;
    if (t < 192) {
        const int br = t >> 6;
        const int d  = t & 63;
        const float* cw  = (br == 0) ? cw0  : (br == 1) ? cw1  : cw2;
        const float* cb  = (br == 0) ? cb0  : (br == 1) ? cb1  : cb2;
        const float* cg  = (br == 0) ? cg0  : (br == 1) ? cg1  : cg2;
        const float* cbe = (br == 0) ? cbe0 : (br == 1) ? cbe1 : cbe2;
        const float* cm  = (br == 0) ? cm0  : (br == 1) ? cm1  : cm2;
        const float* cv  = (br == 0) ? cv0  : (br == 1) ? cv1  : cv2;
        const float* fw  = (br == 0) ? f0w  : (br == 1) ? f1w  : f2w;
        const float s = cg[d] / sqrtf(cv[d] + EPS);
        float* o = W + t * 8;
        #pragma unroll
        for (int k = 0; k < 5; ++k) o[k] = cw[k * 64 + d] * s * LOG2E;
        o[5] = ((cb[d] - cm[d]) * s + cbe[d]) * LOG2E;   // bias, log2 domain
        o[6] = fw[d];                                    // fw   (multiplies exp2 term)
        o[7] = fw[d] * LN2;                              // fw*ln2 (multiplies positive part)
    } else {
        const int d = t - 192;
        const float smp = mpg[d] / sqrtf(mpv[d] + EPS);
        const float A = mpw[d] * smp;
        const float C = (mpb[d] - mpm[d]) * smp + mpbe[d];
        const float s0 = mdg[0] / sqrtf(mdv[0] + EPS);
        const float s1 = mdg[1] / sqrtf(mdv[1] + EPS);
        float* o = W + 1536 + d * 4;
        o[0] = A;
        o[1] = C;
        o[2] = mdw[d * 2 + 0] * s0;
        o[3] = mdw[d * 2 + 1] * s1;
        if (d == 0) {
            W[1795] = (mdb[0] - mdm[0]) * s0 + mdbe[0];
            W[1796] = (mdb[1] - mdm[1]) * s1 + mdbe[1];
        }
    }
    __syncthreads();

    // threads 0..2: per-branch e-range bound + folded init bias
    __shared__ float s_lo[3], s_hi[3];
    if (t < 3) {
        const float* fb_p = (t == 0) ? f0b : (t == 1) ? f1b : f2b;
        const float fb = fb_p[0];
        float sum_fw = 0.0f, S = 0.0f;
        for (int d = 0; d < 64; ++d) {
            const float* o = W + (t * 64 + d) * 8;
            // |h_real| <= ln2 * (sum|taps'| + |bias'|)   (|x| <= 1)
            float hb = LN2 * (fabsf(o[0]) + fabsf(o[1]) + fabsf(o[2]) +
                              fabsf(o[3]) + fabsf(o[4]) + fabsf(o[5]));
            float M = fmaxf(1.0f, hb);   // |elu(h)| <= max(1, hb)
            S += fabsf(o[6]) * M;
            sum_fw += o[6];
        }
        W[1792 + t] = fb - sum_fw;   // FB' (the -1 parts of all elus folded in)
        s_lo[t] = fb - S;
        s_hi[t] = fb + S;
    }
    __syncthreads();
    if (t == 0) {
        float lo = fminf(s_lo[0], fminf(s_lo[1], s_lo[2]));
        float hi = fmaxf(s_hi[0], fmaxf(s_hi[1], s_hi[2]));
        float pad = 1e-3f * (hi - lo) + 1e-6f;
        lo -= pad; hi += pad;
        const float invh = (float)(LUTN - 1) / (hi - lo);
        W[1797] = invh;
        W[1798] = -lo * invh;
        W[1799] = lo;
    }
}

// Build 2048-entry piecewise-linear LUT of F(e) = BN(md . elu(mp*e + ...)).
__global__ void enc_lut(float* __restrict__ W)
{
    const int i = blockIdx.x * blockDim.x + threadIdx.x;
    if (i >= LUTN) return;
    const float lo = W[1799];
    const float h  = 1.0f / W[1797];
    const float D0 = W[1795], D1 = W[1796];
    const float e0 = fmaf((float)i, h, lo);
    const float e1 = fmaf((float)(i + 1), h, lo);
    float a0 = D0, a1 = D1, b0 = D0, b1 = D1;
    for (int d = 0; d < 64; ++d) {
        const float* md = W + 1536 + d * 4;
        const float A = md[0], C = md[1], m0 = md[2], m1 = md[3];
        float u;
        u = elu_plain(fmaf(A, e0, C)); a0 = fmaf(m0, u, a0); a1 = fmaf(m1, u, a1);
        u = elu_plain(fmaf(A, e1, C)); b0 = fmaf(m0, u, b0); b1 = fmaf(m1, u, b1);
    }
    float4* lut = (float4*)(W + 1800);
    lut[i] = make_float4(a0, a1, b0 - a0, b1 - a1);
}

// 2048 blocks x 256 threads; each thread: 1 position, 3 conv branches + LUT modulation.
__global__ __launch_bounds__(256) void enc_main(
    const float* __restrict__ x, const int* __restrict__ perm,
    const float* __restrict__ W, float* __restrict__ out)
{
    __shared__ float xs[LL];
    const int t    = threadIdx.x;
    const int b    = blockIdx.x >> 4;
    const int tile = blockIdx.x & 15;

    // stage full transformed row into LDS (needed for interleaver gathers)
    const float4* xr4 = (const float4*)(x + (size_t)b * LL);
    float4* xs4 = (float4*)xs;
    #pragma unroll
    for (int i = 0; i < 4; ++i) {
        float4 v = xr4[t + 256 * i];
        v.x = 2.0f * v.x - 1.0f;
        v.y = 2.0f * v.y - 1.0f;
        v.z = 2.0f * v.z - 1.0f;
        v.w = 2.0f * v.w - 1.0f;
        xs4[t + 256 * i] = v;
    }
    __syncthreads();

    const int l0 = tile * 256 + t;

    // 5-wide circular window for position l0
    float xw[5], xi[5];
    const int* prow = perm + (size_t)b * LL;
    #pragma unroll
    for (int k = 0; k < 5; ++k) {
        const int idx = (l0 + k - 2) & (LL - 1);
        xw[k] = xs[idx];
        xi[k] = xs[prow[idx]];
    }

    // ---- stage 1: three conv branches -> e0, e1, e2 ----
    // elu(h) = exp2(min(h',0)) - 1 + ln2*max(h',0), taps pre-scaled by log2e,
    // the "-1" terms are folded into FB'.
    float e0 = W[1792], e1 = W[1793], e2 = W[1794];
    #pragma unroll 8
    for (int d = 0; d < 64; ++d) {
        const float* w0 = W + d * 8;
        const float* w1 = W + 512 + d * 8;
        const float* w2 = W + 1024 + d * 8;
        float h, tn, tp;
        h = fmaf(w0[0], xw[0], fmaf(w0[1], xw[1], fmaf(w0[2], xw[2], fmaf(w0[3], xw[3], fmaf(w0[4], xw[4], w0[5])))));
        tn = __builtin_amdgcn_exp2f(fminf(h, 0.0f));
        tp = fmaxf(h, 0.0f);
        e0 = fmaf(w0[6], tn, e0); e0 = fmaf(w0[7], tp, e0);

        h = fmaf(w1[0], xw[0], fmaf(w1[1], xw[1], fmaf(w1[2], xw[2], fmaf(w1[3], xw[3], fmaf(w1[4], xw[4], w1[5])))));
        tn = __builtin_amdgcn_exp2f(fminf(h, 0.0f));
        tp = fmaxf(h, 0.0f);
        e1 = fmaf(w1[6], tn, e1); e1 = fmaf(w1[7], tp, e1);

        h = fmaf(w2[0], xi[0], fmaf(w2[1], xi[1], fmaf(w2[2], xi[2], fmaf(w2[3], xi[3], fmaf(w2[4], xi[4], w2[5])))));
        tn = __builtin_amdgcn_exp2f(fminf(h, 0.0f));
        tp = fmaxf(h, 0.0f);
        e2 = fmaf(w2[6], tn, e2); e2 = fmaf(w2[7], tp, e2);
    }

    // ---- stage 2: F(e) via piecewise-linear LUT ----
    const float invh = W[1797], nlo = W[1798];
    const float4* lut = (const float4*)(W + 1800);
    float2 c0, c1, c2;
    {
        float tt = fminf(fmaxf(fmaf(e0, invh, nlo), 0.0f), (float)(LUTN - 1));
        float fi = floorf(tt); float f = tt - fi;
        float4 v = lut[(int)fi];
        c0.x = fmaf(f, v.z, v.x); c0.y = fmaf(f, v.w, v.y);
    }
    {
        float tt = fminf(fmaxf(fmaf(e1, invh, nlo), 0.0f), (float)(LUTN - 1));
        float fi = floorf(tt); float f = tt - fi;
        float4 v = lut[(int)fi];
        c1.x = fmaf(f, v.z, v.x); c1.y = fmaf(f, v.w, v.y);
    }
    {
        float tt = fminf(fmaxf(fmaf(e2, invh, nlo), 0.0f), (float)(LUTN - 1));
        float fi = floorf(tt); float f = tt - fi;
        float4 v = lut[(int)fi];
        c2.x = fmaf(f, v.z, v.x); c2.y = fmaf(f, v.w, v.y);
    }

    // 6 contiguous floats per thread -> 3x dwordx2, coalesced
    float2* o2 = (float2*)(out + (size_t)b * 24576 + (size_t)l0 * 6);
    o2[0] = c0;
    o2[1] = c1;
    o2[2] = c2;
}

extern "C" void kernel_launch(void* const* d_in, const int* in_sizes, int n_in,
                              void* d_out, int out_size, void* d_ws, size_t ws_size,
                              hipStream_t stream) {
    const float* x    = (const float*)d_in[0];
    const int*   perm = (const int*)d_in[1];
    float* W = (float*)d_ws;

    enc_fold<<<1, 256, 0, stream>>>(
        (const float*)d_in[2],  (const float*)d_in[3],  (const float*)d_in[4],
        (const float*)d_in[5],  (const float*)d_in[6],  (const float*)d_in[7],
        (const float*)d_in[8],  (const float*)d_in[9],  (const float*)d_in[10],
        (const float*)d_in[11], (const float*)d_in[12], (const float*)d_in[13],
        (const float*)d_in[14], (const float*)d_in[15], (const float*)d_in[16],
        (const float*)d_in[17], (const float*)d_in[18], (const float*)d_in[19],
        (const float*)d_in[20], (const float*)d_in[21],
        (const float*)d_in[22], (const float*)d_in[23],
        (const float*)d_in[24], (const float*)d_in[25],
        (const float*)d_in[26], (const float*)d_in[27], (const float*)d_in[28],
        (const float*)d_in[29], (const float*)d_in[30], (const float*)d_in[31],
        (const float*)d_in[32], (const float*)d_in[33], (const float*)d_in[34],
        (const float*)d_in[35], (const float*)d_in[36], (const float*)d_in[37],
        W);

    enc_lut<<<LUTN / 256, 256, 0, stream>>>(W);

    enc_main<<<BATCH * (LL / 256), 256, 0, stream>>>(x, perm, W, (float*)d_out);
}

// Round 4
// 46.496 us; speedup vs baseline: 1.4371x; 1.2069x over previous
//
#include <hip/hip_runtime.h>
#include <math.h>

// Problem constants (from reference)
#define BATCH 128
#define LL    4096
#define DIM   64
#define EPS   1e-3f
#define LUTN  2048

#define LOG2E 1.44269504088896340736f
#define LN2   0.69314718055994530942f

// d_ws layout (floats):
//  [0    .. 3072) : T2[d][3 branches][16] = per (d,branch): 5 taps dup'd as float2
//                   (BN-folded, pre-scaled by log2e), bias dup'd, fw dup'd, fw*ln2 dup'd
//  [3072 .. 3328) : MOD[d][4] = {A_d, C_d, MD_d0, MD_d1}
//  [3328 .. 3331) : FB'[3]    = f_b - sum_d fw_d (per branch)
//  [3331 .. 3333) : D0, D1    = folded md bias+BN
//  [3333]         : invh      (LUT index scale)
//  [3334]         : nlo       (= -lo*invh)
//  [3335]         : lo
//  [3336 .. 3336+4*LUTN) : LUT float4 {F0(e_i), F1(e_i), dF0_i, dF1_i}

typedef float f32x2 __attribute__((ext_vector_type(2)));

__device__ __forceinline__ f32x2 pk_fma(f32x2 a, f32x2 b, f32x2 c) {
    return __builtin_elementwise_fma(a, b, c);
}

__device__ __forceinline__ float elu_plain(float z) {
    return z > 0.0f ? z : (__expf(z) - 1.0f);
}

__global__ void enc_fold(
    const float* __restrict__ cw0, const float* __restrict__ cb0, const float* __restrict__ cg0,
    const float* __restrict__ cbe0, const float* __restrict__ cm0, const float* __restrict__ cv0,
    const float* __restrict__ cw1, const float* __restrict__ cb1, const float* __restrict__ cg1,
    const float* __restrict__ cbe1, const float* __restrict__ cm1, const float* __restrict__ cv1,
    const float* __restrict__ cw2, const float* __restrict__ cb2, const float* __restrict__ cg2,
    const float* __restrict__ cbe2, const float* __restrict__ cm2, const float* __restrict__ cv2,
    const float* __restrict__ f0w, const float* __restrict__ f0b,
    const float* __restrict__ f1w, const float* __restrict__ f1b,
    const float* __restrict__ f2w, const float* __restrict__ f2b,
    const float* __restrict__ mpw, const float* __restrict__ mpb, const float* __restrict__ mpg,
    const float* __restrict__ mpbe, const float* __restrict__ mpm, const float* __restrict__ mpv,
    const float* __restrict__ mdw, const float* __restrict__ mdb, const float* __restrict__ mdg,
    const float* __restrict__ mdbe, const float* __restrict__ mdm, const float* __restrict__ mdv,
    float* __restrict__ W)
{
    const int t = threadIdx.x;
    __shared__ float sS[192];   // |fw|*M bound terms
    __shared__ float sF[192];   // fw terms
    __shared__ float s_lo[3], s_hi[3];

    if (t < 192) {
        const int br = t / 64;
        const int d  = t & 63;
        const float* cw  = (br == 0) ? cw0  : (br == 1) ? cw1  : cw2;
        const float* cb  = (br == 0) ? cb0  : (br == 1) ? cb1  : cb2;
        const float* cg  = (br == 0) ? cg0  : (br == 1) ? cg1  : cg2;
        const float* cbe = (br == 0) ? cbe0 : (br == 1) ? cbe1 : cbe2;
        const float* cm  = (br == 0) ? cm0  : (br == 1) ? cm1  : cm2;
        const float* cv  = (br == 0) ? cv0  : (br == 1) ? cv1  : cv2;
        const float* fw  = (br == 0) ? f0w  : (br == 1) ? f1w  : f2w;
        const float s = cg[d] / sqrtf(cv[d] + EPS);
        float* o = W + d * 48 + br * 16;
        float habs = 0.0f;
        #pragma unroll
        for (int k = 0; k < 5; ++k) {
            const float tap = cw[k * 64 + d] * s * LOG2E;
            o[2 * k] = tap; o[2 * k + 1] = tap;
            habs += fabsf(tap);
        }
        const float bias = ((cb[d] - cm[d]) * s + cbe[d]) * LOG2E;
        o[10] = bias; o[11] = bias;
        const float fwd = fw[d];
        o[12] = fwd; o[13] = fwd;
        const float fwl = fwd * LN2;
        o[14] = fwl; o[15] = fwl;
        const float hb = LN2 * (habs + fabsf(bias));   // bound on |h_real|, |x|<=1
        sS[t] = fabsf(fwd) * fmaxf(1.0f, hb);          // |fw|*|elu(h)| bound
        sF[t] = fwd;
    } else {
        const int d = t - 192;
        const float smp = mpg[d] / sqrtf(mpv[d] + EPS);
        const float A = mpw[d] * smp;
        const float C = (mpb[d] - mpm[d]) * smp + mpbe[d];
        const float s0 = mdg[0] / sqrtf(mdv[0] + EPS);
        const float s1 = mdg[1] / sqrtf(mdv[1] + EPS);
        float* o = W + 3072 + d * 4;
        o[0] = A;
        o[1] = C;
        o[2] = mdw[d * 2 + 0] * s0;
        o[3] = mdw[d * 2 + 1] * s1;
        if (d == 0) {
            W[3331] = (mdb[0] - mdm[0]) * s0 + mdbe[0];
            W[3332] = (mdb[1] - mdm[1]) * s1 + mdbe[1];
        }
    }
    __syncthreads();

    if (t < 3) {
        const float* fb_p = (t == 0) ? f0b : (t == 1) ? f1b : f2b;
        const float fb = fb_p[0];
        float S = 0.0f, sum_fw = 0.0f;
        #pragma unroll 8
        for (int d = 0; d < 64; ++d) {
            S += sS[t * 64 + d];
            sum_fw += sF[t * 64 + d];
        }
        W[3328 + t] = fb - sum_fw;   // FB' (the -1 of every elu folded in)
        s_lo[t] = fb - S;
        s_hi[t] = fb + S;
    }
    __syncthreads();
    if (t == 0) {
        float lo = fminf(s_lo[0], fminf(s_lo[1], s_lo[2]));
        float hi = fmaxf(s_hi[0], fmaxf(s_hi[1], s_hi[2]));
        float pad = 1e-3f * (hi - lo) + 1e-6f;
        lo -= pad; hi += pad;
        const float invh = (float)(LUTN - 1) / (hi - lo);
        W[3333] = invh;
        W[3334] = -lo * invh;
        W[3335] = lo;
    }
}

// Build 2048-entry piecewise-linear LUT of F(e) = BN(md . elu(mp*e + ...)).
__global__ void enc_lut(float* __restrict__ W)
{
    const int i = blockIdx.x * blockDim.x + threadIdx.x;
    if (i >= LUTN) return;
    const float lo = W[3335];
    const float h  = 1.0f / W[3333];
    const float D0 = W[3331], D1 = W[3332];
    const float e0 = fmaf((float)i, h, lo);
    const float e1 = fmaf((float)(i + 1), h, lo);
    float a0 = D0, a1 = D1, b0 = D0, b1 = D1;
    for (int d = 0; d < 64; ++d) {
        const float* md = W + 3072 + d * 4;
        const float A = md[0], C = md[1], m0 = md[2], m1 = md[3];
        float u;
        u = elu_plain(fmaf(A, e0, C)); a0 = fmaf(m0, u, a0); a1 = fmaf(m1, u, a1);
        u = elu_plain(fmaf(A, e1, C)); b0 = fmaf(m0, u, b0); b1 = fmaf(m1, u, b1);
    }
    float4* lut = (float4*)(W + 3336);
    lut[i] = make_float4(a0, a1, b0 - a0, b1 - a1);
}

__device__ __forceinline__ float2 lut_eval(float e, float invh, float nlo,
                                           const float4* __restrict__ lut) {
    float tt = fminf(fmaxf(fmaf(e, invh, nlo), 0.0f), (float)(LUTN - 1));
    float fi = floorf(tt); float f = tt - fi;
    float4 v = lut[(int)fi];
    return make_float2(fmaf(f, v.z, v.x), fmaf(f, v.w, v.y));
}

// 1024 blocks x 256 threads; each thread: 2 adjacent positions via packed-f32 pairs.
__global__ __launch_bounds__(256) void enc_main(
    const float* __restrict__ x, const int* __restrict__ perm,
    const float* __restrict__ W, float* __restrict__ out)
{
    __shared__ float xs[LL];
    const int t    = threadIdx.x;
    const int b    = blockIdx.x >> 3;
    const int tile = blockIdx.x & 7;
    const int l0   = tile * 512 + t * 2;

    // prefetch perm window (global) before the staging barrier
    const int* prow = perm + (size_t)b * LL;
    int pidx[6];
    #pragma unroll
    for (int k = 0; k < 6; ++k) pidx[k] = prow[(l0 + k - 2) & (LL - 1)];

    // stage full transformed row into LDS (needed for interleaver gathers)
    const float4* xr4 = (const float4*)(x + (size_t)b * LL);
    float4* xs4 = (float4*)xs;
    #pragma unroll
    for (int i = 0; i < 4; ++i) {
        float4 v = xr4[t + 256 * i];
        v.x = 2.0f * v.x - 1.0f;
        v.y = 2.0f * v.y - 1.0f;
        v.z = 2.0f * v.z - 1.0f;
        v.w = 2.0f * v.w - 1.0f;
        xs4[t + 256 * i] = v;
    }
    __syncthreads();

    // 6-wide circular windows for positions l0, l0+1 -> shifted pairs
    float xw[6], xiv[6];
    #pragma unroll
    for (int k = 0; k < 6; ++k) {
        xw[k]  = xs[(l0 + k - 2) & (LL - 1)];
        xiv[k] = xs[pidx[k]];
    }
    f32x2 xwp[5], xip[5];
    #pragma unroll
    for (int k = 0; k < 5; ++k) {
        xwp[k] = f32x2{xw[k],  xw[k + 1]};
        xip[k] = f32x2{xiv[k], xiv[k + 1]};
    }

    // ---- stage 1: three conv branches, 2 positions packed ----
    // elu(h) = exp2(min(h',0)) - 1 + ln2*max(h',0); taps pre-scaled by log2e;
    // all "-1" terms folded into FB'.
    f32x2 e0 = f32x2{W[3328], W[3328]};
    f32x2 e1 = f32x2{W[3329], W[3329]};
    f32x2 e2 = f32x2{W[3330], W[3330]};
    const f32x2 zero = f32x2{0.0f, 0.0f};
    #pragma unroll 4
    for (int d = 0; d < 64; ++d) {
        const f32x2* tp = (const f32x2*)W + d * 24;
        f32x2 h, tn, tpv;

        h = pk_fma(tp[0], xwp[0], pk_fma(tp[1], xwp[1], pk_fma(tp[2], xwp[2],
            pk_fma(tp[3], xwp[3], pk_fma(tp[4], xwp[4], tp[5])))));
        tn = __builtin_elementwise_min(h, zero);
        tn.x = __builtin_amdgcn_exp2f(tn.x);
        tn.y = __builtin_amdgcn_exp2f(tn.y);
        tpv = __builtin_elementwise_max(h, zero);
        e0 = pk_fma(tp[6], tn, e0);
        e0 = pk_fma(tp[7], tpv, e0);

        h = pk_fma(tp[8], xwp[0], pk_fma(tp[9], xwp[1], pk_fma(tp[10], xwp[2],
            pk_fma(tp[11], xwp[3], pk_fma(tp[12], xwp[4], tp[13])))));
        tn = __builtin_elementwise_min(h, zero);
        tn.x = __builtin_amdgcn_exp2f(tn.x);
        tn.y = __builtin_amdgcn_exp2f(tn.y);
        tpv = __builtin_elementwise_max(h, zero);
        e1 = pk_fma(tp[14], tn, e1);
        e1 = pk_fma(tp[15], tpv, e1);

        h = pk_fma(tp[16], xip[0], pk_fma(tp[17], xip[1], pk_fma(tp[18], xip[2],
            pk_fma(tp[19], xip[3], pk_fma(tp[20], xip[4], tp[21])))));
        tn = __builtin_elementwise_min(h, zero);
        tn.x = __builtin_amdgcn_exp2f(tn.x);
        tn.y = __builtin_amdgcn_exp2f(tn.y);
        tpv = __builtin_elementwise_max(h, zero);
        e2 = pk_fma(tp[22], tn, e2);
        e2 = pk_fma(tp[23], tpv, e2);
    }

    // ---- stage 2: F(e) via piecewise-linear LUT (6 scalars) ----
    const float invh = W[3333], nlo = W[3334];
    const float4* lut = (const float4*)(W + 3336);
    float2 r0 = lut_eval(e0.x, invh, nlo, lut);
    float2 r1 = lut_eval(e1.x, invh, nlo, lut);
    float2 r2 = lut_eval(e2.x, invh, nlo, lut);
    float2 r3 = lut_eval(e0.y, invh, nlo, lut);
    float2 r4 = lut_eval(e1.y, invh, nlo, lut);
    float2 r5 = lut_eval(e2.y, invh, nlo, lut);

    // 12 contiguous floats per thread -> 3x dwordx4, coalesced
    float4* o4 = (float4*)(out + (size_t)b * 24576 + (size_t)l0 * 6);
    o4[0] = make_float4(r0.x, r0.y, r1.x, r1.y);
    o4[1] = make_float4(r2.x, r2.y, r3.x, r3.y);
    o4[2] = make_float4(r4.x, r4.y, r5.x, r5.y);
}

extern "C" void kernel_launch(void* const* d_in, const int* in_sizes, int n_in,
                              void* d_out, int out_size, void* d_ws, size_t ws_size,
                              hipStream_t stream) {
    const float* x    = (const float*)d_in[0];
    const int*   perm = (const int*)d_in[1];
    float* W = (float*)d_ws;

    enc_fold<<<1, 256, 0, stream>>>(
        (const float*)d_in[2],  (const float*)d_in[3],  (const float*)d_in[4],
        (const float*)d_in[5],  (const float*)d_in[6],  (const float*)d_in[7],
        (const float*)d_in[8],  (const float*)d_in[9],  (const float*)d_in[10],
        (const float*)d_in[11], (const float*)d_in[12], (const float*)d_in[13],
        (const float*)d_in[14], (const float*)d_in[15], (const float*)d_in[16],
        (const float*)d_in[17], (const float*)d_in[18], (const float*)d_in[19],
        (const float*)d_in[20], (const float*)d_in[21],
        (const float*)d_in[22], (const float*)d_in[23],
        (const float*)d_in[24], (const float*)d_in[25],
        (const float*)d_in[26], (const float*)d_in[27], (const float*)d_in[28],
        (const float*)d_in[29], (const float*)d_in[30], (const float*)d_in[31],
        (const float*)d_in[32], (const float*)d_in[33], (const float*)d_in[34],
        (const float*)d_in[35], (const float*)d_in[36], (const float*)d_in[37],
        W);

    enc_lut<<<LUTN / 256, 256, 0, stream>>>(W);

    enc_main<<<BATCH * (LL / 512), 256, 0, stream>>>(x, perm, W, (float*)d_out);
}

// Round 5
// 40.537 us; speedup vs baseline: 1.6484x; 1.1470x over previous
//
#include <hip/hip_runtime.h>
#include <math.h>

// Problem constants (from reference)
#define BATCH 128
#define LL    4096
#define DIM   64
#define EPS   1e-3f
#define LUTN  2048

#define LOG2E 1.44269504088896340736f
#define LN2   0.69314718055994530942f

// d_ws layout (floats):
//  [0    .. 1536) : T[j][br][16], j = channel-pair 0..31, br = 0..2:
//                   {T0.lo,T0.hi, T1.., T2.., T3.., T4.., Bias.., Fw.., FwLn2..}
//                   pair = channels (2j, 2j+1); taps BN-folded, pre-scaled by log2e
//  [1792 .. 1795) : FB'[3] = f_b - sum_d fw_d (per branch; all elu "-1" folded)
//  [1795 .. 1797) : D0, D1 (folded md bias+BN; for reference only)
//  [1797]         : invh   (LUT index scale)
//  [1798]         : nlo    (= -lo*invh)
//  [1799]         : lo
//  [1800 .. 1800+4*LUTN) : LUT float4 {F0(e_i), F1(e_i), dF0_i, dF1_i}

typedef float f32x2 __attribute__((ext_vector_type(2)));

__device__ __forceinline__ f32x2 pk_fma(f32x2 a, f32x2 b, f32x2 c) {
    return __builtin_elementwise_fma(a, b, c);
}

__device__ __forceinline__ float elu_plain(float z) {
    return z > 0.0f ? z : (__expf(z) - 1.0f);
}

// ONE prologue kernel, 8 blocks x 256 threads.
// Every block redundantly folds (cheap) so it can build its LUT slice locally;
// block 0 additionally writes the folded weights/constants to W.
__global__ __launch_bounds__(256) void enc_prep(
    const float* __restrict__ cw0, const float* __restrict__ cb0, const float* __restrict__ cg0,
    const float* __restrict__ cbe0, const float* __restrict__ cm0, const float* __restrict__ cv0,
    const float* __restrict__ cw1, const float* __restrict__ cb1, const float* __restrict__ cg1,
    const float* __restrict__ cbe1, const float* __restrict__ cm1, const float* __restrict__ cv1,
    const float* __restrict__ cw2, const float* __restrict__ cb2, const float* __restrict__ cg2,
    const float* __restrict__ cbe2, const float* __restrict__ cm2, const float* __restrict__ cv2,
    const float* __restrict__ f0w, const float* __restrict__ f0b,
    const float* __restrict__ f1w, const float* __restrict__ f1b,
    const float* __restrict__ f2w, const float* __restrict__ f2b,
    const float* __restrict__ mpw, const float* __restrict__ mpb, const float* __restrict__ mpg,
    const float* __restrict__ mpbe, const float* __restrict__ mpm, const float* __restrict__ mpv,
    const float* __restrict__ mdw, const float* __restrict__ mdb, const float* __restrict__ mdg,
    const float* __restrict__ mdbe, const float* __restrict__ mdm, const float* __restrict__ mdv,
    float* __restrict__ W)
{
    const int t   = threadIdx.x;
    const int blk = blockIdx.x;
    __shared__ float smod[64][4];          // {A, C, m0, m1}
    __shared__ float s_lo[3], s_hi[3];
    __shared__ float sD[2];
    __shared__ float srange[2];            // lo, hstep

    if (t < 192) {
        const int br = t >> 6;             // wave-aligned: wave 0,1,2 = branch 0,1,2
        const int d  = t & 63;
        const float* cw  = (br == 0) ? cw0  : (br == 1) ? cw1  : cw2;
        const float* cb  = (br == 0) ? cb0  : (br == 1) ? cb1  : cb2;
        const float* cg  = (br == 0) ? cg0  : (br == 1) ? cg1  : cg2;
        const float* cbe = (br == 0) ? cbe0 : (br == 1) ? cbe1 : cbe2;
        const float* cm  = (br == 0) ? cm0  : (br == 1) ? cm1  : cm2;
        const float* cv  = (br == 0) ? cv0  : (br == 1) ? cv1  : cv2;
        const float* fw  = (br == 0) ? f0w  : (br == 1) ? f1w  : f2w;
        const float s = cg[d] / sqrtf(cv[d] + EPS);
        float tap[5], habs = 0.0f;
        #pragma unroll
        for (int k = 0; k < 5; ++k) {
            tap[k] = cw[k * 64 + d] * s * LOG2E;
            habs += fabsf(tap[k]);
        }
        const float bias = ((cb[d] - cm[d]) * s + cbe[d]) * LOG2E;
        const float fwd  = fw[d];
        if (blk == 0) {
            float* o = W + ((d >> 1) * 3 + br) * 16 + (d & 1);
            o[0] = tap[0]; o[2] = tap[1]; o[4] = tap[2]; o[6] = tap[3]; o[8] = tap[4];
            o[10] = bias; o[12] = fwd; o[14] = fwd * LN2;
        }
        const float hb = LN2 * (habs + fabsf(bias));   // bound on |h_real|, |x|<=1
        float myS = fabsf(fwd) * fmaxf(1.0f, hb);      // |fw * elu(h)| bound
        float myF = fwd;
        #pragma unroll
        for (int off = 32; off; off >>= 1) {
            myS += __shfl_down(myS, off);
            myF += __shfl_down(myF, off);
        }
        if ((t & 63) == 0) {
            const float fb = ((br == 0) ? f0b : (br == 1) ? f1b : f2b)[0];
            s_lo[br] = fb - myS;
            s_hi[br] = fb + myS;
            if (blk == 0) W[1792 + br] = fb - myF;     // FB'
        }
    } else {
        const int d = t - 192;
        const float smp = mpg[d] / sqrtf(mpv[d] + EPS);
        const float A = mpw[d] * smp;
        const float C = (mpb[d] - mpm[d]) * smp + mpbe[d];
        const float s0 = mdg[0] / sqrtf(mdv[0] + EPS);
        const float s1 = mdg[1] / sqrtf(mdv[1] + EPS);
        smod[d][0] = A;
        smod[d][1] = C;
        smod[d][2] = mdw[d * 2 + 0] * s0;
        smod[d][3] = mdw[d * 2 + 1] * s1;
        if (d == 0) {
            const float D0 = (mdb[0] - mdm[0]) * s0 + mdbe[0];
            const float D1 = (mdb[1] - mdm[1]) * s1 + mdbe[1];
            sD[0] = D0; sD[1] = D1;
            if (blk == 0) { W[1795] = D0; W[1796] = D1; }
        }
    }
    __syncthreads();

    if (t == 0) {
        float lo = fminf(s_lo[0], fminf(s_lo[1], s_lo[2]));
        float hi = fmaxf(s_hi[0], fmaxf(s_hi[1], s_hi[2]));
        float pad = 1e-3f * (hi - lo) + 1e-6f;
        lo -= pad; hi += pad;
        srange[0] = lo;
        srange[1] = (hi - lo) / (float)(LUTN - 1);
        if (blk == 0) {
            const float invh = (float)(LUTN - 1) / (hi - lo);
            W[1797] = invh;
            W[1798] = -lo * invh;
            W[1799] = lo;
        }
    }
    __syncthreads();

    // LUT slice: entry i for this thread
    const int i = blk * 256 + t;
    const float lo = srange[0], hs = srange[1];
    const float D0 = sD[0], D1 = sD[1];
    const float e0 = fmaf((float)i, hs, lo);
    const float e1 = fmaf((float)(i + 1), hs, lo);
    float a0 = D0, a1 = D1, b0 = D0, b1 = D1;
    #pragma unroll 8
    for (int d = 0; d < 64; ++d) {
        const float A = smod[d][0], C = smod[d][1], m0 = smod[d][2], m1 = smod[d][3];
        float u;
        u = elu_plain(fmaf(A, e0, C)); a0 = fmaf(m0, u, a0); a1 = fmaf(m1, u, a1);
        u = elu_plain(fmaf(A, e1, C)); b0 = fmaf(m0, u, b0); b1 = fmaf(m1, u, b1);
    }
    float4* lut = (float4*)(W + 1800);
    lut[i] = make_float4(a0, a1, b0 - a0, b1 - a1);
}

__device__ __forceinline__ float2 lut_eval(float e, float invh, float nlo,
                                           const float4* __restrict__ lut) {
    float tt = fminf(fmaxf(fmaf(e, invh, nlo), 0.0f), (float)(LUTN - 1));
    float fi = floorf(tt); float f = tt - fi;
    float4 v = lut[(int)fi];
    return make_float2(fmaf(f, v.z, v.x), fmaf(f, v.w, v.y));
}

// 2048 blocks x 256 threads; 1 position/thread, channel-pair packed f32 math.
// No LDS, no barrier: windows and interleaver gathers read straight from
// global (x is 2MB -> L2-resident). 32-waves/CU occupancy cap.
__global__ __launch_bounds__(256) void enc_main(
    const float* __restrict__ x, const int* __restrict__ perm,
    const float* __restrict__ W, float* __restrict__ out)
{
    const int gid = blockIdx.x * 256 + threadIdx.x;
    const int b   = gid >> 12;
    const int l0  = gid & (LL - 1);
    const float* xrow = x + ((size_t)b << 12);
    const int*   prow = perm + ((size_t)b << 12);

    // 5-wide circular windows: systematic (xw) and interleaved (gather)
    int pidx[5];
    #pragma unroll
    for (int k = 0; k < 5; ++k) pidx[k] = prow[(l0 + k - 2) & (LL - 1)];
    float xw[5], xg[5];
    #pragma unroll
    for (int k = 0; k < 5; ++k) {
        xw[k] = fmaf(2.0f, xrow[(l0 + k - 2) & (LL - 1)], -1.0f);
        xg[k] = fmaf(2.0f, xrow[pidx[k]], -1.0f);
    }
    // loop-invariant splat pairs (channel packing: same x for both halves)
    f32x2 xwp[5], xip[5];
    #pragma unroll
    for (int k = 0; k < 5; ++k) {
        xwp[k] = f32x2{xw[k], xw[k]};
        xip[k] = f32x2{xg[k], xg[k]};
    }

    // ---- stage 1: three conv branches, channels packed in pairs ----
    // elu(h) = exp2(min(h',0)) - 1 + ln2*max(h',0); taps pre-scaled by log2e;
    // all "-1" terms folded into FB'.
    f32x2 e0 = f32x2{0.0f, 0.0f};
    f32x2 e1 = f32x2{0.0f, 0.0f};
    f32x2 e2 = f32x2{0.0f, 0.0f};
    const f32x2 zero = f32x2{0.0f, 0.0f};
    #pragma unroll 4
    for (int j = 0; j < 32; ++j) {
        const f32x2* tp = (const f32x2*)W + j * 24;
        f32x2 h, tn, tq;

        h = pk_fma(tp[0], xwp[0], pk_fma(tp[1], xwp[1], pk_fma(tp[2], xwp[2],
            pk_fma(tp[3], xwp[3], pk_fma(tp[4], xwp[4], tp[5])))));
        tn = __builtin_elementwise_min(h, zero);
        tn.x = __builtin_amdgcn_exp2f(tn.x);
        tn.y = __builtin_amdgcn_exp2f(tn.y);
        tq = __builtin_elementwise_max(h, zero);
        e0 = pk_fma(tp[6], tn, e0);
        e0 = pk_fma(tp[7], tq, e0);

        h = pk_fma(tp[8], xwp[0], pk_fma(tp[9], xwp[1], pk_fma(tp[10], xwp[2],
            pk_fma(tp[11], xwp[3], pk_fma(tp[12], xwp[4], tp[13])))));
        tn = __builtin_elementwise_min(h, zero);
        tn.x = __builtin_amdgcn_exp2f(tn.x);
        tn.y = __builtin_amdgcn_exp2f(tn.y);
        tq = __builtin_elementwise_max(h, zero);
        e1 = pk_fma(tp[14], tn, e1);
        e1 = pk_fma(tp[15], tq, e1);

        h = pk_fma(tp[16], xip[0], pk_fma(tp[17], xip[1], pk_fma(tp[18], xip[2],
            pk_fma(tp[19], xip[3], pk_fma(tp[20], xip[4], tp[21])))));
        tn = __builtin_elementwise_min(h, zero);
        tn.x = __builtin_amdgcn_exp2f(tn.x);
        tn.y = __builtin_amdgcn_exp2f(tn.y);
        tq = __builtin_elementwise_max(h, zero);
        e2 = pk_fma(tp[22], tn, e2);
        e2 = pk_fma(tp[23], tq, e2);
    }
    const float s0 = W[1792] + e0.x + e0.y;
    const float s1 = W[1793] + e1.x + e1.y;
    const float s2 = W[1794] + e2.x + e2.y;

    // ---- stage 2: F(e) via piecewise-linear LUT ----
    const float invh = W[1797], nlo = W[1798];
    const float4* lut = (const float4*)(W + 1800);
    float2 r0 = lut_eval(s0, invh, nlo, lut);
    float2 r1 = lut_eval(s1, invh, nlo, lut);
    float2 r2 = lut_eval(s2, invh, nlo, lut);

    // 6 contiguous floats per thread, thread-consecutive -> coalesced
    float2* o2 = (float2*)(out + (size_t)gid * 6);
    o2[0] = r0;
    o2[1] = r1;
    o2[2] = r2;
}

extern "C" void kernel_launch(void* const* d_in, const int* in_sizes, int n_in,
                              void* d_out, int out_size, void* d_ws, size_t ws_size,
                              hipStream_t stream) {
    const float* x    = (const float*)d_in[0];
    const int*   perm = (const int*)d_in[1];
    float* W = (float*)d_ws;

    enc_prep<<<LUTN / 256, 256, 0, stream>>>(
        (const float*)d_in[2],  (const float*)d_in[3],  (const float*)d_in[4],
        (const float*)d_in[5],  (const float*)d_in[6],  (const float*)d_in[7],
        (const float*)d_in[8],  (const float*)d_in[9],  (const float*)d_in[10],
        (const float*)d_in[11], (const float*)d_in[12], (const float*)d_in[13],
        (const float*)d_in[14], (const float*)d_in[15], (const float*)d_in[16],
        (const float*)d_in[17], (const float*)d_in[18], (const float*)d_in[19],
        (const float*)d_in[20], (const float*)d_in[21],
        (const float*)d_in[22], (const float*)d_in[23],
        (const float*)d_in[24], (const float*)d_in[25],
        (const float*)d_in[26], (const float*)d_in[27], (const float*)d_in[28],
        (const float*)d_in[29], (const float*)d_in[30], (const float*)d_in[31],
        (const float*)d_in[32], (const float*)d_in[33], (const float*)d_in[34],
        (const float*)d_in[35], (const float*)d_in[36], (const float*)d_in[37],
        W);

    enc_main<<<(BATCH * LL) / 256, 256, 0, stream>>>(x, perm, W, (float*)d_out);
}

// Round 7
// 38.061 us; speedup vs baseline: 1.7556x; 1.0650x over previous
//
#include <hip/hip_runtime.h>
#include <math.h>

// Problem constants (from reference)
#define BATCH 128
#define LL    4096
#define DIM   64
#define EPS   1e-3f
#define LUTN  2048

#define LOG2E 1.44269504088896340736f
#define LN2   0.69314718055994530942f

// Taylor coefficients of s(z) = (exp2(z)-1-ln2*z)/z^2  (z in [-1, 0])
#define GC2 0.2402265069591007f     // ln2^2/2
#define GC3 0.05550410866482158f    // ln2^3/6
#define GC4 0.009618129107628477f   // ln2^4/24
#define GC5 0.0013333558146428443f  // ln2^5/120
#define GC6 1.540353039338161e-4f   // ln2^6/720
#define GC7 1.525273380405984e-5f   // ln2^7/5040

// d_ws layout (floats):
//  [0    .. 1536) : T[j][br][16], j = channel-pair 0..31, br = 0..2:
//                   {T0.lo,T0.hi, T1.., T2.., T3.., T4.., Bias.., Fw.., FwLn2..}
//                   pair = channels (2j, 2j+1); taps BN-folded, pre-scaled by log2e
//  [1792 .. 1795) : FB[3]  = f_b (plain dense bias; poly accumulator holds fw*elu exactly)
//  [1795 .. 1797) : D0, D1 (folded md bias+BN)
//  [1797]         : invh   (LUT index scale)
//  [1798]         : nlo    (= -lo*invh)
//  [1799]         : lo
//  [1800 .. 1800+4*LUTN) : LUT float4 {F0(e_i), F1(e_i), dF0_i, dF1_i}

typedef float f32x2 __attribute__((ext_vector_type(2)));

__device__ __forceinline__ f32x2 pk_fma(f32x2 a, f32x2 b, f32x2 c) {
    return __builtin_elementwise_fma(a, b, c);
}

__device__ __forceinline__ float elu_plain(float z) {
    return z > 0.0f ? z : (__expf(z) - 1.0f);
}

// ONE prologue kernel, 8 blocks x 256 threads.
// Every block redundantly folds (cheap) so it can build its LUT slice locally;
// block 0 additionally writes the folded weights/constants to W.
__global__ __launch_bounds__(256) void enc_prep(
    const float* __restrict__ cw0, const float* __restrict__ cb0, const float* __restrict__ cg0,
    const float* __restrict__ cbe0, const float* __restrict__ cm0, const float* __restrict__ cv0,
    const float* __restrict__ cw1, const float* __restrict__ cb1, const float* __restrict__ cg1,
    const float* __restrict__ cbe1, const float* __restrict__ cm1, const float* __restrict__ cv1,
    const float* __restrict__ cw2, const float* __restrict__ cb2, const float* __restrict__ cg2,
    const float* __restrict__ cbe2, const float* __restrict__ cm2, const float* __restrict__ cv2,
    const float* __restrict__ f0w, const float* __restrict__ f0b,
    const float* __restrict__ f1w, const float* __restrict__ f1b,
    const float* __restrict__ f2w, const float* __restrict__ f2b,
    const float* __restrict__ mpw, const float* __restrict__ mpb, const float* __restrict__ mpg,
    const float* __restrict__ mpbe, const float* __restrict__ mpm, const float* __restrict__ mpv,
    const float* __restrict__ mdw, const float* __restrict__ mdb, const float* __restrict__ mdg,
    const float* __restrict__ mdbe, const float* __restrict__ mdm, const float* __restrict__ mdv,
    float* __restrict__ W)
{
    const int t   = threadIdx.x;
    const int blk = blockIdx.x;
    __shared__ float smod[64][4];          // {A, C, m0, m1}
    __shared__ float s_lo[3], s_hi[3];
    __shared__ float sD[2];
    __shared__ float srange[2];            // lo, hstep

    if (t < 192) {
        const int br = t >> 6;             // wave-aligned: wave 0,1,2 = branch 0,1,2
        const int d  = t & 63;
        const float* cw  = (br == 0) ? cw0  : (br == 1) ? cw1  : cw2;
        const float* cb  = (br == 0) ? cb0  : (br == 1) ? cb1  : cb2;
        const float* cg  = (br == 0) ? cg0  : (br == 1) ? cg1  : cg2;
        const float* cbe = (br == 0) ? cbe0 : (br == 1) ? cbe1 : cbe2;
        const float* cm  = (br == 0) ? cm0  : (br == 1) ? cm1  : cm2;
        const float* cv  = (br == 0) ? cv0  : (br == 1) ? cv1  : cv2;
        const float* fw  = (br == 0) ? f0w  : (br == 1) ? f1w  : f2w;
        const float s = cg[d] / sqrtf(cv[d] + EPS);
        float tap[5], habs = 0.0f;
        #pragma unroll
        for (int k = 0; k < 5; ++k) {
            tap[k] = cw[k * 64 + d] * s * LOG2E;
            habs += fabsf(tap[k]);
        }
        const float bias = ((cb[d] - cm[d]) * s + cbe[d]) * LOG2E;
        const float fwd  = fw[d];
        if (blk == 0) {
            float* o = W + ((d >> 1) * 3 + br) * 16 + (d & 1);
            o[0] = tap[0]; o[2] = tap[1]; o[4] = tap[2]; o[6] = tap[3]; o[8] = tap[4];
            o[10] = bias; o[12] = fwd; o[14] = fwd * LN2;
        }
        const float hb = LN2 * (habs + fabsf(bias));   // bound on |h_real|, |x|<=1
        float myS = fabsf(fwd) * fmaxf(1.0f, hb);      // |fw * elu(h)| bound
        #pragma unroll
        for (int off = 32; off; off >>= 1) {
            myS += __shfl_down(myS, off);
        }
        if ((t & 63) == 0) {
            const float fb = ((br == 0) ? f0b : (br == 1) ? f1b : f2b)[0];
            s_lo[br] = fb - myS;
            s_hi[br] = fb + myS;
            if (blk == 0) W[1792 + br] = fb;   // plain fb: poly acc holds fw*elu exactly
        }
    } else {
        const int d = t - 192;
        const float smp = mpg[d] / sqrtf(mpv[d] + EPS);
        const float A = mpw[d] * smp;
        const float C = (mpb[d] - mpm[d]) * smp + mpbe[d];
        const float s0 = mdg[0] / sqrtf(mdv[0] + EPS);
        const float s1 = mdg[1] / sqrtf(mdv[1] + EPS);
        smod[d][0] = A;
        smod[d][1] = C;
        smod[d][2] = mdw[d * 2 + 0] * s0;
        smod[d][3] = mdw[d * 2 + 1] * s1;
        if (d == 0) {
            const float D0 = (mdb[0] - mdm[0]) * s0 + mdbe[0];
            const float D1 = (mdb[1] - mdm[1]) * s1 + mdbe[1];
            sD[0] = D0; sD[1] = D1;
            if (blk == 0) { W[1795] = D0; W[1796] = D1; }
        }
    }
    __syncthreads();

    if (t == 0) {
        float lo = fminf(s_lo[0], fminf(s_lo[1], s_lo[2]));
        float hi = fmaxf(s_hi[0], fmaxf(s_hi[1], s_hi[2]));
        float pad = 1e-3f * (hi - lo) + 1e-6f;
        lo -= pad; hi += pad;
        srange[0] = lo;
        srange[1] = (hi - lo) / (float)(LUTN - 1);
        if (blk == 0) {
            const float invh = (float)(LUTN - 1) / (hi - lo);
            W[1797] = invh;
            W[1798] = -lo * invh;
            W[1799] = lo;
        }
    }
    __syncthreads();

    // LUT slice: entry i for this thread
    const int i = blk * 256 + t;
    const float lo = srange[0], hs = srange[1];
    const float D0 = sD[0], D1 = sD[1];
    const float e0 = fmaf((float)i, hs, lo);
    const float e1 = fmaf((float)(i + 1), hs, lo);
    float a0 = D0, a1 = D1, b0 = D0, b1 = D1;
    #pragma unroll 8
    for (int d = 0; d < 64; ++d) {
        const float A = smod[d][0], C = smod[d][1], m0 = smod[d][2], m1 = smod[d][3];
        float u;
        u = elu_plain(fmaf(A, e0, C)); a0 = fmaf(m0, u, a0); a1 = fmaf(m1, u, a1);
        u = elu_plain(fmaf(A, e1, C)); b0 = fmaf(m0, u, b0); b1 = fmaf(m1, u, b1);
    }
    float4* lut = (float4*)(W + 1800);
    lut[i] = make_float4(a0, a1, b0 - a0, b1 - a1);
}

__device__ __forceinline__ float2 lut_eval(float e, float invh, float nlo,
                                           const float4* __restrict__ lut) {
    float tt = fminf(fmaxf(fmaf(e, invh, nlo), 0.0f), (float)(LUTN - 1));
    float fi = floorf(tt); float f = tt - fi;
    float4 v = lut[(int)fi];
    return make_float2(fmaf(f, v.z, v.x), fmaf(f, v.w, v.y));
}

// elu contribution via polynomial (no transcendental):
// fw*elu(h) = fw * z^2 * s(z) + fw*ln2 * h',  z = min(h',0)  (exact identity + Taylor tail)
__device__ __forceinline__ void elu_acc(f32x2 h, f32x2 fw, f32x2 fwl, f32x2& e,
                                        const f32x2 zero) {
    f32x2 z  = __builtin_elementwise_min(h, zero);
    f32x2 zz = z * z;
    f32x2 s  = pk_fma(z, f32x2{GC7, GC7}, f32x2{GC6, GC6});
    s = pk_fma(z, s, f32x2{GC5, GC5});
    s = pk_fma(z, s, f32x2{GC4, GC4});
    s = pk_fma(z, s, f32x2{GC3, GC3});
    s = pk_fma(z, s, f32x2{GC2, GC2});
    e = pk_fma(fw, zz * s, e);
    e = pk_fma(fwl, h, e);
}

// 1024 blocks x 256 threads; 2 positions/thread, channel-pair packed f32 math,
// polynomial ELU tail (no v_exp). No LDS: x (2MB) is L2-resident.
__global__ __launch_bounds__(256) void enc_main(
    const float* __restrict__ x, const int* __restrict__ perm,
    const float* __restrict__ W, float* __restrict__ out)
{
    const int gid = blockIdx.x * 256 + threadIdx.x;   // pair index
    const int b   = gid >> 11;
    const int l0  = (gid & (2048 - 1)) * 2;
    const float* xrow = x + ((size_t)b << 12);
    const int*   prow = perm + ((size_t)b << 12);

    // 6-wide circular windows for positions l0, l0+1
    int pidx[6];
    #pragma unroll
    for (int k = 0; k < 6; ++k) pidx[k] = prow[(l0 + k - 2) & (LL - 1)];
    float xw[6], xg[6];
    #pragma unroll
    for (int k = 0; k < 6; ++k) {
        xw[k] = fmaf(2.0f, xrow[(l0 + k - 2) & (LL - 1)], -1.0f);
        xg[k] = fmaf(2.0f, xrow[pidx[k]], -1.0f);
    }
    // channel-pair packing: both halves carry the same x value
    f32x2 xs[6], xi[6];
    #pragma unroll
    for (int k = 0; k < 6; ++k) {
        xs[k] = f32x2{xw[k], xw[k]};
        xi[k] = f32x2{xg[k], xg[k]};
    }

    // accumulators: [branch][pos], each f32x2 over the channel pair
    f32x2 eA0 = {0.0f, 0.0f}, eA1 = {0.0f, 0.0f};
    f32x2 eB0 = {0.0f, 0.0f}, eB1 = {0.0f, 0.0f};
    f32x2 eC0 = {0.0f, 0.0f}, eC1 = {0.0f, 0.0f};
    const f32x2 zero = {0.0f, 0.0f};

    #pragma unroll 4
    for (int j = 0; j < 32; ++j) {
        const f32x2* tp = (const f32x2*)W + j * 24;
        f32x2 h;

        // branch 0 (systematic), positions l0 and l0+1 share taps
        h = pk_fma(tp[0], xs[0], pk_fma(tp[1], xs[1], pk_fma(tp[2], xs[2],
            pk_fma(tp[3], xs[3], pk_fma(tp[4], xs[4], tp[5])))));
        elu_acc(h, tp[6], tp[7], eA0, zero);
        h = pk_fma(tp[0], xs[1], pk_fma(tp[1], xs[2], pk_fma(tp[2], xs[3],
            pk_fma(tp[3], xs[4], pk_fma(tp[4], xs[5], tp[5])))));
        elu_acc(h, tp[6], tp[7], eA1, zero);

        // branch 1 (systematic)
        h = pk_fma(tp[8], xs[0], pk_fma(tp[9], xs[1], pk_fma(tp[10], xs[2],
            pk_fma(tp[11], xs[3], pk_fma(tp[12], xs[4], tp[13])))));
        elu_acc(h, tp[14], tp[15], eB0, zero);
        h = pk_fma(tp[8], xs[1], pk_fma(tp[9], xs[2], pk_fma(tp[10], xs[3],
            pk_fma(tp[11], xs[4], pk_fma(tp[12], xs[5], tp[13])))));
        elu_acc(h, tp[14], tp[15], eB1, zero);

        // branch 2 (interleaved)
        h = pk_fma(tp[16], xi[0], pk_fma(tp[17], xi[1], pk_fma(tp[18], xi[2],
            pk_fma(tp[19], xi[3], pk_fma(tp[20], xi[4], tp[21])))));
        elu_acc(h, tp[22], tp[23], eC0, zero);
        h = pk_fma(tp[16], xi[1], pk_fma(tp[17], xi[2], pk_fma(tp[18], xi[3],
            pk_fma(tp[19], xi[4], pk_fma(tp[20], xi[5], tp[21])))));
        elu_acc(h, tp[22], tp[23], eC1, zero);
    }

    const float fbA = W[1792], fbB = W[1793], fbC = W[1794];
    const float sA0 = fbA + eA0.x + eA0.y, sA1 = fbA + eA1.x + eA1.y;
    const float sB0 = fbB + eB0.x + eB0.y, sB1 = fbB + eB1.x + eB1.y;
    const float sC0 = fbC + eC0.x + eC0.y, sC1 = fbC + eC1.x + eC1.y;

    // ---- stage 2: F(e) via piecewise-linear LUT ----
    const float invh = W[1797], nlo = W[1798];
    const float4* lut = (const float4*)(W + 1800);
    float2 r0 = lut_eval(sA0, invh, nlo, lut);
    float2 r1 = lut_eval(sB0, invh, nlo, lut);
    float2 r2 = lut_eval(sC0, invh, nlo, lut);
    float2 r3 = lut_eval(sA1, invh, nlo, lut);
    float2 r4 = lut_eval(sB1, invh, nlo, lut);
    float2 r5 = lut_eval(sC1, invh, nlo, lut);

    // 12 contiguous floats per thread -> 3x dwordx4
    float4* o4 = (float4*)(out + (size_t)gid * 12);
    o4[0] = make_float4(r0.x, r0.y, r1.x, r1.y);
    o4[1] = make_float4(r2.x, r2.y, r3.x, r3.y);
    o4[2] = make_float4(r4.x, r4.y, r5.x, r5.y);
}

extern "C" void kernel_launch(void* const* d_in, const int* in_sizes, int n_in,
                              void* d_out, int out_size, void* d_ws, size_t ws_size,
                              hipStream_t stream) {
    const float* x    = (const float*)d_in[0];
    const int*   perm = (const int*)d_in[1];
    float* W = (float*)d_ws;

    enc_prep<<<LUTN / 256, 256, 0, stream>>>(
        (const float*)d_in[2],  (const float*)d_in[3],  (const float*)d_in[4],
        (const float*)d_in[5],  (const float*)d_in[6],  (const float*)d_in[7],
        (const float*)d_in[8],  (const float*)d_in[9],  (const float*)d_in[10],
        (const float*)d_in[11], (const float*)d_in[12], (const float*)d_in[13],
        (const float*)d_in[14], (const float*)d_in[15], (const float*)d_in[16],
        (const float*)d_in[17], (const float*)d_in[18], (const float*)d_in[19],
        (const float*)d_in[20], (const float*)d_in[21],
        (const float*)d_in[22], (const float*)d_in[23],
        (const float*)d_in[24], (const float*)d_in[25],
        (const float*)d_in[26], (const float*)d_in[27], (const float*)d_in[28],
        (const float*)d_in[29], (const float*)d_in[30], (const float*)d_in[31],
        (const float*)d_in[32], (const float*)d_in[33], (const float*)d_in[34],
        (const float*)d_in[35], (const float*)d_in[36], (const float*)d_in[37],
        W);

    enc_main<<<(BATCH * LL) / 512, 256, 0, stream>>>(x, perm, W, (float*)d_out);
}

// Round 8
// 35.686 us; speedup vs baseline: 1.8724x; 1.0666x over previous
//
#include <hip/hip_runtime.h>
#include <math.h>

// Problem constants (from reference)
#define BATCH 128
#define LL    4096
#define DIM   64
#define EPS   1e-3f
#define LUTN  2048

#define LOG2E 1.44269504088896340736f
#define LN2   0.69314718055994530942f

// Taylor coefficients of s(z) = (exp2(z)-1-ln2*z)/z^2  (z in [-1, 0])
#define GC2 0.2402265069591007f     // ln2^2/2
#define GC3 0.05550410866482158f    // ln2^3/6
#define GC4 0.009618129107628477f   // ln2^4/24
#define GC5 0.0013333558146428443f  // ln2^5/120

// d_ws layout (floats):
//  [0    .. 1536) : T[j][br][16], j = channel-pair 0..31, br = 0..2:
//                   {T0.lo,T0.hi, .., T4.lo,T4.hi, Bias.lo,.hi, Fw.lo,.hi, pad, pad}
//                   taps BN-folded, pre-scaled by log2e
//  [1536 .. 1560) : LIN[3][8] = {ct0..ct4, cb, pad, pad} per branch:
//                   collapsed linear filter ct_k = ln2*sum_d fw_d*tap'_dk,
//                   cb = ln2*sum_d fw_d*bias'_d
//  [1560 .. 1563) : FB[3]  = f_b (plain dense bias)
//  [1563 .. 1565) : D0, D1 (folded md bias+BN)
//  [1565]         : invh   (LUT index scale)
//  [1566]         : nlo    (= -lo*invh)
//  [1567]         : lo
//  [1568 .. 1568+4*LUTN) : LUT float4 {F0(e_i), F1(e_i), dF0_i, dF1_i}

typedef float f32x2 __attribute__((ext_vector_type(2)));

__device__ __forceinline__ f32x2 pk_fma(f32x2 a, f32x2 b, f32x2 c) {
    return __builtin_elementwise_fma(a, b, c);
}

__device__ __forceinline__ float elu_plain(float z) {
    return z > 0.0f ? z : (__expf(z) - 1.0f);
}

// ONE prologue kernel, 8 blocks x 256 threads.
__global__ __launch_bounds__(256) void enc_prep(
    const float* __restrict__ cw0, const float* __restrict__ cb0, const float* __restrict__ cg0,
    const float* __restrict__ cbe0, const float* __restrict__ cm0, const float* __restrict__ cv0,
    const float* __restrict__ cw1, const float* __restrict__ cb1, const float* __restrict__ cg1,
    const float* __restrict__ cbe1, const float* __restrict__ cm1, const float* __restrict__ cv1,
    const float* __restrict__ cw2, const float* __restrict__ cb2, const float* __restrict__ cg2,
    const float* __restrict__ cbe2, const float* __restrict__ cm2, const float* __restrict__ cv2,
    const float* __restrict__ f0w, const float* __restrict__ f0b,
    const float* __restrict__ f1w, const float* __restrict__ f1b,
    const float* __restrict__ f2w, const float* __restrict__ f2b,
    const float* __restrict__ mpw, const float* __restrict__ mpb, const float* __restrict__ mpg,
    const float* __restrict__ mpbe, const float* __restrict__ mpm, const float* __restrict__ mpv,
    const float* __restrict__ mdw, const float* __restrict__ mdb, const float* __restrict__ mdg,
    const float* __restrict__ mdbe, const float* __restrict__ mdm, const float* __restrict__ mdv,
    float* __restrict__ W)
{
    const int t   = threadIdx.x;
    const int blk = blockIdx.x;
    __shared__ float smod[64][4];          // {A, C, m0, m1}
    __shared__ float s_lo[3], s_hi[3];
    __shared__ float sD[2];
    __shared__ float srange[2];            // lo, hstep

    if (t < 192) {
        const int br = t >> 6;             // wave-aligned: wave 0,1,2 = branch 0,1,2
        const int d  = t & 63;
        const float* cw  = (br == 0) ? cw0  : (br == 1) ? cw1  : cw2;
        const float* cb  = (br == 0) ? cb0  : (br == 1) ? cb1  : cb2;
        const float* cg  = (br == 0) ? cg0  : (br == 1) ? cg1  : cg2;
        const float* cbe = (br == 0) ? cbe0 : (br == 1) ? cbe1 : cbe2;
        const float* cm  = (br == 0) ? cm0  : (br == 1) ? cm1  : cm2;
        const float* cv  = (br == 0) ? cv0  : (br == 1) ? cv1  : cv2;
        const float* fw  = (br == 0) ? f0w  : (br == 1) ? f1w  : f2w;
        const float s = cg[d] / sqrtf(cv[d] + EPS);
        float tap[5], habs = 0.0f;
        #pragma unroll
        for (int k = 0; k < 5; ++k) {
            tap[k] = cw[k * 64 + d] * s * LOG2E;
            habs += fabsf(tap[k]);
        }
        const float bias = ((cb[d] - cm[d]) * s + cbe[d]) * LOG2E;
        const float fwd  = fw[d];
        if (blk == 0) {
            float* o = W + ((d >> 1) * 3 + br) * 16 + (d & 1);
            o[0] = tap[0]; o[2] = tap[1]; o[4] = tap[2]; o[6] = tap[3]; o[8] = tap[4];
            o[10] = bias; o[12] = fwd;
        }
        const float hb = LN2 * (habs + fabsf(bias));   // bound on |h_real|, |x|<=1
        // reductions over the 64-lane branch wave:
        float r0 = fwd * tap[0], r1 = fwd * tap[1], r2 = fwd * tap[2];
        float r3 = fwd * tap[3], r4 = fwd * tap[4], rb = fwd * bias;
        float myS = fabsf(fwd) * fmaxf(1.0f, hb);      // |fw * elu(h)| bound
        #pragma unroll
        for (int off = 32; off; off >>= 1) {
            r0 += __shfl_down(r0, off);
            r1 += __shfl_down(r1, off);
            r2 += __shfl_down(r2, off);
            r3 += __shfl_down(r3, off);
            r4 += __shfl_down(r4, off);
            rb += __shfl_down(rb, off);
            myS += __shfl_down(myS, off);
        }
        if ((t & 63) == 0) {
            const float fb = ((br == 0) ? f0b : (br == 1) ? f1b : f2b)[0];
            s_lo[br] = fb - myS;
            s_hi[br] = fb + myS;
            if (blk == 0) {
                float* Lb = W + 1536 + br * 8;
                Lb[0] = LN2 * r0; Lb[1] = LN2 * r1; Lb[2] = LN2 * r2;
                Lb[3] = LN2 * r3; Lb[4] = LN2 * r4; Lb[5] = LN2 * rb;
                W[1560 + br] = fb;
            }
        }
    } else {
        const int d = t - 192;
        const float smp = mpg[d] / sqrtf(mpv[d] + EPS);
        const float A = mpw[d] * smp;
        const float C = (mpb[d] - mpm[d]) * smp + mpbe[d];
        const float s0 = mdg[0] / sqrtf(mdv[0] + EPS);
        const float s1 = mdg[1] / sqrtf(mdv[1] + EPS);
        smod[d][0] = A;
        smod[d][1] = C;
        smod[d][2] = mdw[d * 2 + 0] * s0;
        smod[d][3] = mdw[d * 2 + 1] * s1;
        if (d == 0) {
            const float D0 = (mdb[0] - mdm[0]) * s0 + mdbe[0];
            const float D1 = (mdb[1] - mdm[1]) * s1 + mdbe[1];
            sD[0] = D0; sD[1] = D1;
            if (blk == 0) { W[1563] = D0; W[1564] = D1; }
        }
    }
    __syncthreads();

    if (t == 0) {
        float lo = fminf(s_lo[0], fminf(s_lo[1], s_lo[2]));
        float hi = fmaxf(s_hi[0], fmaxf(s_hi[1], s_hi[2]));
        float pad = 1e-3f * (hi - lo) + 1e-6f;
        lo -= pad; hi += pad;
        srange[0] = lo;
        srange[1] = (hi - lo) / (float)(LUTN - 1);
        if (blk == 0) {
            const float invh = (float)(LUTN - 1) / (hi - lo);
            W[1565] = invh;
            W[1566] = -lo * invh;
            W[1567] = lo;
        }
    }
    __syncthreads();

    // LUT slice: entry i for this thread
    const int i = blk * 256 + t;
    const float lo = srange[0], hs = srange[1];
    const float D0 = sD[0], D1 = sD[1];
    const float e0 = fmaf((float)i, hs, lo);
    const float e1 = fmaf((float)(i + 1), hs, lo);
    float a0 = D0, a1 = D1, b0 = D0, b1 = D1;
    #pragma unroll 8
    for (int d = 0; d < 64; ++d) {
        const float A = smod[d][0], C = smod[d][1], m0 = smod[d][2], m1 = smod[d][3];
        float u;
        u = elu_plain(fmaf(A, e0, C)); a0 = fmaf(m0, u, a0); a1 = fmaf(m1, u, a1);
        u = elu_plain(fmaf(A, e1, C)); b0 = fmaf(m0, u, b0); b1 = fmaf(m1, u, b1);
    }
    float4* lut = (float4*)(W + 1568);
    lut[i] = make_float4(a0, a1, b0 - a0, b1 - a1);
}

__device__ __forceinline__ float2 lut_eval(float e, float invh, float nlo,
                                           const float4* __restrict__ lut) {
    float tt = fminf(fmaxf(fmaf(e, invh, nlo), 0.0f), (float)(LUTN - 1));
    float fi = floorf(tt); float f = tt - fi;
    float4 v = lut[(int)fi];
    return make_float2(fmaf(f, v.z, v.x), fmaf(f, v.w, v.y));
}

// nonlinear elu remainder: fw * z^2 * s(z), z = min(h',0), deg-3 Taylor tail
__device__ __forceinline__ void nl_acc(f32x2 h, f32x2 fw, f32x2& e) {
    const f32x2 zero = {0.0f, 0.0f};
    f32x2 z  = __builtin_elementwise_min(h, zero);
    f32x2 zz = z * z;
    f32x2 s  = pk_fma(z, f32x2{GC5, GC5}, f32x2{GC4, GC4});
    s = pk_fma(z, s, f32x2{GC3, GC3});
    s = pk_fma(z, s, f32x2{GC2, GC2});
    e = pk_fma(fw, zz * s, e);
}

// 1024 blocks x 256 threads; 2 positions/thread, channel-pair packed f32 math.
// Linear part of all 64 channels collapsed into one 5-tap filter per branch.
__global__ __launch_bounds__(256) void enc_main(
    const float* __restrict__ x, const int* __restrict__ perm,
    const float* __restrict__ W, float* __restrict__ out)
{
    const int gid = blockIdx.x * 256 + threadIdx.x;   // position-pair index
    const int b   = gid >> 11;
    const int l0  = (gid & (2048 - 1)) * 2;
    const float* xrow = x + ((size_t)b << 12);
    const int*   prow = perm + ((size_t)b << 12);

    // 6-wide circular windows via 3x 8B vector loads (bases even, no intra-pair wrap)
    const int ba = (l0 - 2) & (LL - 1);
    const int bc = (l0 + 2) & (LL - 1);
    const float2 w01 = *(const float2*)(xrow + ba);
    const float2 w23 = *(const float2*)(xrow + l0);
    const float2 w45 = *(const float2*)(xrow + bc);
    const int2 p01 = *(const int2*)(prow + ba);
    const int2 p23 = *(const int2*)(prow + l0);
    const int2 p45 = *(const int2*)(prow + bc);

    float xw[6], xg[6];
    xw[0] = fmaf(2.0f, w01.x, -1.0f); xw[1] = fmaf(2.0f, w01.y, -1.0f);
    xw[2] = fmaf(2.0f, w23.x, -1.0f); xw[3] = fmaf(2.0f, w23.y, -1.0f);
    xw[4] = fmaf(2.0f, w45.x, -1.0f); xw[5] = fmaf(2.0f, w45.y, -1.0f);
    xg[0] = fmaf(2.0f, xrow[p01.x], -1.0f); xg[1] = fmaf(2.0f, xrow[p01.y], -1.0f);
    xg[2] = fmaf(2.0f, xrow[p23.x], -1.0f); xg[3] = fmaf(2.0f, xrow[p23.y], -1.0f);
    xg[4] = fmaf(2.0f, xrow[p45.x], -1.0f); xg[5] = fmaf(2.0f, xrow[p45.y], -1.0f);

    // channel-pair packing: both halves carry the same x value
    f32x2 xs[6], xi[6];
    #pragma unroll
    for (int k = 0; k < 6; ++k) {
        xs[k] = f32x2{xw[k], xw[k]};
        xi[k] = f32x2{xg[k], xg[k]};
    }

    // collapsed linear part per (branch, pos)
    const float* LA = W + 1536;
    const float* LB = W + 1544;
    const float* LC = W + 1552;
    float linA0 = fmaf(LA[0], xw[0], fmaf(LA[1], xw[1], fmaf(LA[2], xw[2],
                  fmaf(LA[3], xw[3], fmaf(LA[4], xw[4], LA[5])))));
    float linA1 = fmaf(LA[0], xw[1], fmaf(LA[1], xw[2], fmaf(LA[2], xw[3],
                  fmaf(LA[3], xw[4], fmaf(LA[4], xw[5], LA[5])))));
    float linB0 = fmaf(LB[0], xw[0], fmaf(LB[1], xw[1], fmaf(LB[2], xw[2],
                  fmaf(LB[3], xw[3], fmaf(LB[4], xw[4], LB[5])))));
    float linB1 = fmaf(LB[0], xw[1], fmaf(LB[1], xw[2], fmaf(LB[2], xw[3],
                  fmaf(LB[3], xw[4], fmaf(LB[4], xw[5], LB[5])))));
    float linC0 = fmaf(LC[0], xg[0], fmaf(LC[1], xg[1], fmaf(LC[2], xg[2],
                  fmaf(LC[3], xg[3], fmaf(LC[4], xg[4], LC[5])))));
    float linC1 = fmaf(LC[0], xg[1], fmaf(LC[1], xg[2], fmaf(LC[2], xg[3],
                  fmaf(LC[3], xg[4], fmaf(LC[4], xg[5], LC[5])))));

    // nonlinear accumulators: [branch][pos], f32x2 over the channel pair
    f32x2 eA0 = {0.0f, 0.0f}, eA1 = {0.0f, 0.0f};
    f32x2 eB0 = {0.0f, 0.0f}, eB1 = {0.0f, 0.0f};
    f32x2 eC0 = {0.0f, 0.0f}, eC1 = {0.0f, 0.0f};

    #pragma unroll 4
    for (int j = 0; j < 32; ++j) {
        const f32x2* tp = (const f32x2*)W + j * 24;
        f32x2 h;

        // branch 0 (systematic): taps tp[0..4], bias tp[5], fw tp[6]
        h = pk_fma(tp[0], xs[0], pk_fma(tp[1], xs[1], pk_fma(tp[2], xs[2],
            pk_fma(tp[3], xs[3], pk_fma(tp[4], xs[4], tp[5])))));
        nl_acc(h, tp[6], eA0);
        h = pk_fma(tp[0], xs[1], pk_fma(tp[1], xs[2], pk_fma(tp[2], xs[3],
            pk_fma(tp[3], xs[4], pk_fma(tp[4], xs[5], tp[5])))));
        nl_acc(h, tp[6], eA1);

        // branch 1 (systematic): tp[8..12], tp[13], tp[14]
        h = pk_fma(tp[8], xs[0], pk_fma(tp[9], xs[1], pk_fma(tp[10], xs[2],
            pk_fma(tp[11], xs[3], pk_fma(tp[12], xs[4], tp[13])))));
        nl_acc(h, tp[14], eB0);
        h = pk_fma(tp[8], xs[1], pk_fma(tp[9], xs[2], pk_fma(tp[10], xs[3],
            pk_fma(tp[11], xs[4], pk_fma(tp[12], xs[5], tp[13])))));
        nl_acc(h, tp[14], eB1);

        // branch 2 (interleaved): tp[16..20], tp[21], tp[22]
        h = pk_fma(tp[16], xi[0], pk_fma(tp[17], xi[1], pk_fma(tp[18], xi[2],
            pk_fma(tp[19], xi[3], pk_fma(tp[20], xi[4], tp[21])))));
        nl_acc(h, tp[22], eC0);
        h = pk_fma(tp[16], xi[1], pk_fma(tp[17], xi[2], pk_fma(tp[18], xi[3],
            pk_fma(tp[19], xi[4], pk_fma(tp[20], xi[5], tp[21])))));
        nl_acc(h, tp[22], eC1);
    }

    const float fbA = W[1560], fbB = W[1561], fbC = W[1562];
    const float sA0 = fbA + linA0 + eA0.x + eA0.y;
    const float sA1 = fbA + linA1 + eA1.x + eA1.y;
    const float sB0 = fbB + linB0 + eB0.x + eB0.y;
    const float sB1 = fbB + linB1 + eB1.x + eB1.y;
    const float sC0 = fbC + linC0 + eC0.x + eC0.y;
    const float sC1 = fbC + linC1 + eC1.x + eC1.y;

    // ---- stage 2: F(e) via piecewise-linear LUT ----
    const float invh = W[1565], nlo = W[1566];
    const float4* lut = (const float4*)(W + 1568);
    float2 r0 = lut_eval(sA0, invh, nlo, lut);
    float2 r1 = lut_eval(sB0, invh, nlo, lut);
    float2 r2 = lut_eval(sC0, invh, nlo, lut);
    float2 r3 = lut_eval(sA1, invh, nlo, lut);
    float2 r4 = lut_eval(sB1, invh, nlo, lut);
    float2 r5 = lut_eval(sC1, invh, nlo, lut);

    // 12 contiguous floats per thread -> 3x dwordx4
    float4* o4 = (float4*)(out + (size_t)gid * 12);
    o4[0] = make_float4(r0.x, r0.y, r1.x, r1.y);
    o4[1] = make_float4(r2.x, r2.y, r3.x, r3.y);
    o4[2] = make_float4(r4.x, r4.y, r5.x, r5.y);
}

extern "C" void kernel_launch(void* const* d_in, const int* in_sizes, int n_in,
                              void* d_out, int out_size, void* d_ws, size_t ws_size,
                              hipStream_t stream) {
    const float* x    = (const float*)d_in[0];
    const int*   perm = (const int*)d_in[1];
    float* W = (float*)d_ws;

    enc_prep<<<LUTN / 256, 256, 0, stream>>>(
        (const float*)d_in[2],  (const float*)d_in[3],  (const float*)d_in[4],
        (const float*)d_in[5],  (const float*)d_in[6],  (const float*)d_in[7],
        (const float*)d_in[8],  (const float*)d_in[9],  (const float*)d_in[10],
        (const float*)d_in[11], (const float*)d_in[12], (const float*)d_in[13],
        (const float*)d_in[14], (const float*)d_in[15], (const float*)d_in[16],
        (const float*)d_in[17], (const float*)d_in[18], (const float*)d_in[19],
        (const float*)d_in[20], (const float*)d_in[21],
        (const float*)d_in[22], (const float*)d_in[23],
        (const float*)d_in[24], (const float*)d_in[25],
        (const float*)d_in[26], (const float*)d_in[27], (const float*)d_in[28],
        (const float*)d_in[29], (const float*)d_in[30], (const float*)d_in[31],
        (const float*)d_in[32], (const float*)d_in[33], (const float*)d_in[34],
        (const float*)d_in[35], (const float*)d_in[36], (const float*)d_in[37],
        W);

    enc_main<<<(BATCH * LL) / 512, 256, 0, stream>>>(x, perm, W, (float*)d_out);
}